// Round 3
// baseline (433.685 us; speedup 1.0000x reference)
//
#include <hip/hip_runtime.h>
#include <math.h>

#define N_NODES 50000
#define F_DIM 64
#define E_EDGES 800000
#define U_DIM 128
#define K_DIM 192
#define EPS_LN 0.001f

// ---------------- dtype probe ----------------
// If edge_indices arrived as int64 (LE, values in [0, 2^31)), odd 32-bit words
// of the buffer are all zero. If int32 [r,s] pairs, odd words are send indices.
__global__ void probe_kernel(const int* __restrict__ e, int* __restrict__ flag) {
    __shared__ int nz;
    if (threadIdx.x == 0) nz = 0;
    __syncthreads();
    int i = threadIdx.x;               // 256 threads -> first 256 edges either way
    if (e[4 * i + 1] != 0 || e[4 * i + 3] != 0) atomicAdd(&nz, 1);
    __syncthreads();
    if (threadIdx.x == 0) flag[0] = (nz == 0) ? 1 : 0;   // 1 = int64 layout
}

// ---------------- CSR build ----------------

__global__ void hist_kernel(const int* __restrict__ edges, int* __restrict__ cnt,
                            const int* __restrict__ flag, int E) {
    int i = blockIdx.x * blockDim.x + threadIdx.x;
    if (i >= E) return;
    int is64 = flag[0];
    int r = is64 ? edges[4 * i] : edges[2 * i];
    atomicAdd(&cnt[r], 1);
}

// Single-block exclusive scan over cnt[N] -> row_start[N+1], copy into cursor[N].
__global__ void scan_kernel(const int* __restrict__ cnt, int* __restrict__ row_start,
                            int* __restrict__ cursor, int N) {
    const int T = 1024;
    int tid = threadIdx.x;
    int C = (N + T - 1) / T;              // elements per thread (49)
    int lo = tid * C;
    int hi = lo + C; if (hi > N) hi = N;

    int local = 0;
    for (int i = lo; i < hi; ++i) local += cnt[i];

    int lane = tid & 63, wid = tid >> 6;   // 16 waves
    int v = local;
    #pragma unroll
    for (int off = 1; off < 64; off <<= 1) {
        int y = __shfl_up(v, off, 64);
        if (lane >= off) v += y;
    }
    __shared__ int wsum[16];
    if (lane == 63) wsum[wid] = v;
    __syncthreads();
    if (wid == 0 && lane < 16) {
        int wv = wsum[lane];
        #pragma unroll
        for (int off = 1; off < 16; off <<= 1) {
            int y = __shfl_up(wv, off, 64);
            if (lane >= off) wv += y;
        }
        wsum[lane] = wv;   // inclusive wave sums
    }
    __syncthreads();
    int base = (wid > 0 ? wsum[wid - 1] : 0) + (v - local);

    int run = base;
    for (int i = lo; i < hi; ++i) {
        row_start[i] = run;
        cursor[i] = run;
        run += cnt[i];
    }
    if (tid == 0) row_start[N] = wsum[15];
}

__global__ void scatter_kernel(const int* __restrict__ edges, int* __restrict__ cursor,
                               int* __restrict__ edge_send, const int* __restrict__ flag, int E) {
    int i = blockIdx.x * blockDim.x + threadIdx.x;
    if (i >= E) return;
    int is64 = flag[0];
    int r, s;
    if (is64) { r = edges[4 * i]; s = edges[4 * i + 2]; }
    else      { r = edges[2 * i]; s = edges[2 * i + 1]; }
    int pos = atomicAdd(&cursor[r], 1);
    edge_send[pos] = s;
}

// ---------------- Per-node aggregation: one wave per node, lane = feature ----------------

__global__ void aggregate_kernel(const float* __restrict__ attr, const int* __restrict__ row_start,
                                 const int* __restrict__ edge_send, float* __restrict__ X,
                                 float* __restrict__ scaleArr, int N) {
    int gwid = (blockIdx.x * blockDim.x + threadIdx.x) >> 6;   // global wave id = node
    int lane = threadIdx.x & 63;
    if (gwid >= N) return;
    int beg = row_start[gwid], end = row_start[gwid + 1];
    float sum = 0.f, mx = -INFINITY;
    int e = beg;
    // 4-deep manual unroll: issue 4 index loads, then 4 independent gathers (MLP)
    for (; e + 4 <= end; e += 4) {
        int s0 = edge_send[e + 0];
        int s1 = edge_send[e + 1];
        int s2 = edge_send[e + 2];
        int s3 = edge_send[e + 3];
        float v0 = attr[(size_t)s0 * F_DIM + lane];
        float v1 = attr[(size_t)s1 * F_DIM + lane];
        float v2 = attr[(size_t)s2 * F_DIM + lane];
        float v3 = attr[(size_t)s3 * F_DIM + lane];
        sum += v0 + v1 + v2 + v3;
        mx = fmaxf(mx, fmaxf(fmaxf(v0, v1), fmaxf(v2, v3)));
    }
    for (; e < end; ++e) {
        int s = edge_send[e];
        float vv = attr[(size_t)s * F_DIM + lane];
        sum += vv;
        mx = fmaxf(mx, vv);
    }
    int c = end - beg;
    float deg = fmaxf((float)c, 1.f);
    float mean = sum / deg;
    if (c == 0) mx = 0.f;
    float* xr = X + (size_t)gwid * K_DIM;
    xr[lane] = mean;
    xr[64 + lane] = mx;
    xr[128 + lane] = sum;
    if (lane == 0) scaleArr[gwid] = logf(deg + 1.f) * 0.43429448190325176f;  // log10(deg+1)
}

// ---------------- Weight folding: Wa = [W0;W3;W6], Wb = [W1+W2;W4+W5;W7+W8] ----------------

__global__ void wprep_kernel(const float* __restrict__ W, float* __restrict__ Wa, float* __restrict__ Wb) {
    int i = blockIdx.x * blockDim.x + threadIdx.x;
    if (i >= K_DIM * U_DIM) return;
    int k = i >> 7, c = i & 127;
    int g = k >> 6, r = k & 63;
    int base = g * 192 + r;                 // rows of W (576x128)
    Wa[i] = W[(size_t)base * U_DIM + c];
    Wb[i] = W[(size_t)(base + 64) * U_DIM + c] + W[(size_t)(base + 128) * U_DIM + c];
}

// ---------------- GEMM: out = relu(X@Wa + scale*(X@Wb) + b), 64x128 tile ----------------

__launch_bounds__(256)
__global__ void gemm_kernel(const float* __restrict__ X, const float* __restrict__ Wa,
                            const float* __restrict__ Wb, const float* __restrict__ scaleArr,
                            const float* __restrict__ bias, float* __restrict__ out, int N) {
    __shared__ float Xs[32][64];      // [k][m]
    __shared__ float Was[32][128];
    __shared__ float Wbs[32][128];
    int tid = threadIdx.x;
    int tx = tid & 15, ty = tid >> 4;   // 16x16 threads
    int m0 = blockIdx.x * 64;

    float accA[4][8];
    float accB[4][8];
    #pragma unroll
    for (int r = 0; r < 4; ++r)
        #pragma unroll
        for (int c = 0; c < 8; ++c) { accA[r][c] = 0.f; accB[r][c] = 0.f; }

    for (int kb = 0; kb < K_DIM / 32; ++kb) {
        #pragma unroll
        for (int j = 0; j < 2; ++j) {
            int idx = tid + j * 256;            // 0..511
            int row = idx >> 3, kq = idx & 7;
            int gr = m0 + row;
            float4 xv = make_float4(0.f, 0.f, 0.f, 0.f);
            if (gr < N) xv = *(const float4*)&X[(size_t)gr * K_DIM + kb * 32 + kq * 4];
            int k0 = kq * 4;
            Xs[k0 + 0][row] = xv.x;
            Xs[k0 + 1][row] = xv.y;
            Xs[k0 + 2][row] = xv.z;
            Xs[k0 + 3][row] = xv.w;
        }
        #pragma unroll
        for (int j = 0; j < 4; ++j) {
            int idx = tid + j * 256;            // 0..1023
            int kr = idx >> 5, cq = idx & 31;
            *(float4*)&Was[kr][cq * 4] = *(const float4*)&Wa[(size_t)(kb * 32 + kr) * U_DIM + cq * 4];
            *(float4*)&Wbs[kr][cq * 4] = *(const float4*)&Wb[(size_t)(kb * 32 + kr) * U_DIM + cq * 4];
        }
        __syncthreads();
        #pragma unroll
        for (int kk = 0; kk < 32; ++kk) {
            float4 xv = *(const float4*)&Xs[kk][ty * 4];
            float4 a0 = *(const float4*)&Was[kk][tx * 4];
            float4 a1 = *(const float4*)&Was[kk][tx * 4 + 64];
            float4 b0 = *(const float4*)&Wbs[kk][tx * 4];
            float4 b1 = *(const float4*)&Wbs[kk][tx * 4 + 64];
            float xr[4] = {xv.x, xv.y, xv.z, xv.w};
            float wa[8] = {a0.x, a0.y, a0.z, a0.w, a1.x, a1.y, a1.z, a1.w};
            float wb[8] = {b0.x, b0.y, b0.z, b0.w, b1.x, b1.y, b1.z, b1.w};
            #pragma unroll
            for (int r = 0; r < 4; ++r)
                #pragma unroll
                for (int c = 0; c < 8; ++c) {
                    accA[r][c] = fmaf(xr[r], wa[c], accA[r][c]);
                    accB[r][c] = fmaf(xr[r], wb[c], accB[r][c]);
                }
        }
        __syncthreads();
    }

    float4 bv0 = *(const float4*)&bias[tx * 4];
    float4 bv1 = *(const float4*)&bias[tx * 4 + 64];
    float bb[8] = {bv0.x, bv0.y, bv0.z, bv0.w, bv1.x, bv1.y, bv1.z, bv1.w};
    #pragma unroll
    for (int r = 0; r < 4; ++r) {
        int gr = m0 + ty * 4 + r;
        if (gr >= N) continue;
        float sc = scaleArr[gr];
        float o[8];
        #pragma unroll
        for (int c = 0; c < 8; ++c)
            o[c] = fmaxf(fmaf(sc, accB[r][c], accA[r][c]) + bb[c], 0.f);
        *(float4*)&out[(size_t)gr * U_DIM + tx * 4]      = make_float4(o[0], o[1], o[2], o[3]);
        *(float4*)&out[(size_t)gr * U_DIM + tx * 4 + 64] = make_float4(o[4], o[5], o[6], o[7]);
    }
}

// ---------------- BatchNorm over axis 0 ----------------

__global__ void stats_kernel(const float* __restrict__ h, float* __restrict__ stats, int N) {
    int c = threadIdx.x & 127;
    int half = threadIdx.x >> 7;          // 0/1
    int r0 = blockIdx.x * 128 + half;
    int r1 = blockIdx.x * 128 + 128; if (r1 > N) r1 = N;
    float s = 0.f, s2 = 0.f;
    for (int r = r0; r < r1; r += 2) {
        float v = h[(size_t)r * U_DIM + c];
        s += v;
        s2 = fmaf(v, v, s2);
    }
    atomicAdd(&stats[c], s);
    atomicAdd(&stats[128 + c], s2);
}

__global__ void finalize_kernel(const float* __restrict__ stats, float* __restrict__ ab,
                                const float* __restrict__ gamma, const float* __restrict__ beta, int N) {
    int c = threadIdx.x;   // 128 threads
    float inv = 1.f / (float)N;
    float mean = stats[c] * inv;
    float var = stats[128 + c] * inv - mean * mean;
    float rstd = rsqrtf(var + EPS_LN);
    float sc = gamma[c] * rstd;
    ab[c] = sc;
    ab[128 + c] = fmaf(-mean, sc, beta[c]);
}

__global__ void norm_kernel(float* __restrict__ h, const float* __restrict__ ab, int total4) {
    int i = blockIdx.x * blockDim.x + threadIdx.x;
    if (i >= total4) return;
    int c0 = (i * 4) & 127;
    float4 v = ((const float4*)h)[i];
    float4 o;
    o.x = fmaf(v.x, ab[c0 + 0], ab[128 + c0 + 0]);
    o.y = fmaf(v.y, ab[c0 + 1], ab[128 + c0 + 1]);
    o.z = fmaf(v.z, ab[c0 + 2], ab[128 + c0 + 2]);
    o.w = fmaf(v.w, ab[c0 + 3], ab[128 + c0 + 3]);
    ((float4*)h)[i] = o;
}

// ---------------- launch ----------------

extern "C" void kernel_launch(void* const* d_in, const int* in_sizes, int n_in,
                              void* d_out, int out_size, void* d_ws, size_t ws_size,
                              hipStream_t stream) {
    const float* attr        = (const float*)d_in[0];
    const int*   edges       = (const int*)d_in[1];   // int32 or int64 (probed)
    const float* W           = (const float*)d_in[2];
    const float* bias        = (const float*)d_in[3];
    const float* gamma       = (const float*)d_in[4];
    const float* beta        = (const float*)d_in[5];
    float* out = (float*)d_out;

    const int N = N_NODES, E = E_EDGES;

    char* ws = (char*)d_ws;
    size_t off = 0;
    auto alloc = [&](size_t bytes) -> void* {
        void* p = ws + off;
        off = (off + bytes + 255) & ~(size_t)255;
        return p;
    };
    int*   cnt       = (int*)alloc((size_t)N * 4);
    int*   row_start = (int*)alloc((size_t)(N + 1) * 4);
    int*   cursor    = (int*)alloc((size_t)N * 4);
    int*   edge_send = (int*)alloc((size_t)E * 4);
    float* scaleArr  = (float*)alloc((size_t)N * 4);
    float* stats     = (float*)alloc(512 * 4);   // sums, sumsq, then ab(scale/shift)
    int*   flag      = (int*)alloc(256);
    float* Wa        = (float*)alloc((size_t)K_DIM * U_DIM * 4);
    float* Wb        = (float*)alloc((size_t)K_DIM * U_DIM * 4);
    float* X         = (float*)alloc((size_t)N * K_DIM * 4);
    float* ab        = stats + 256;

    hipMemsetAsync(cnt, 0, (size_t)N * 4, stream);
    hipMemsetAsync(stats, 0, 512 * 4, stream);

    probe_kernel<<<1, 256, 0, stream>>>(edges, flag);
    hist_kernel<<<(E + 255) / 256, 256, 0, stream>>>(edges, cnt, flag, E);
    scan_kernel<<<1, 1024, 0, stream>>>(cnt, row_start, cursor, N);
    scatter_kernel<<<(E + 255) / 256, 256, 0, stream>>>(edges, cursor, edge_send, flag, E);
    aggregate_kernel<<<(N + 3) / 4, 256, 0, stream>>>(attr, row_start, edge_send, X, scaleArr, N);
    wprep_kernel<<<(K_DIM * U_DIM + 255) / 256, 256, 0, stream>>>(W, Wa, Wb);
    gemm_kernel<<<(N + 63) / 64, 256, 0, stream>>>(X, Wa, Wb, scaleArr, bias, out, N);
    stats_kernel<<<(N + 127) / 128, 256, 0, stream>>>(out, stats, N);
    finalize_kernel<<<1, 128, 0, stream>>>(stats, ab, gamma, beta, N);
    norm_kernel<<<(N * U_DIM / 4 + 255) / 256, 256, 0, stream>>>(out, ab, N * U_DIM / 4);
}

// Round 6
// 391.412 us; speedup vs baseline: 1.1080x; 1.1080x over previous
//
#include <hip/hip_runtime.h>
#include <math.h>

#define N_NODES 50000
#define F_DIM 64
#define E_EDGES 800000
#define U_DIM 128
#define K_DIM 192
#define EPS_LN 0.001f

typedef __attribute__((ext_vector_type(8))) short bf16x8;
typedef __attribute__((ext_vector_type(4))) float f32x4;
typedef __attribute__((ext_vector_type(8))) unsigned short us8;

__device__ __forceinline__ unsigned short f2bf(float x) {
    unsigned u = __builtin_bit_cast(unsigned, x);
    unsigned r = (u + 0x7FFFu + ((u >> 16) & 1u)) >> 16;   // RNE
    return (unsigned short)r;
}
__device__ __forceinline__ float bf2f(unsigned short h) {
    unsigned u = ((unsigned)h) << 16;
    return __builtin_bit_cast(float, u);
}

// ---------------- dtype probe ----------------
__global__ void probe_kernel(const int* __restrict__ e, int* __restrict__ flag) {
    __shared__ int nz;
    if (threadIdx.x == 0) nz = 0;
    __syncthreads();
    int i = threadIdx.x;
    if (e[4 * i + 1] != 0 || e[4 * i + 3] != 0) atomicAdd(&nz, 1);
    __syncthreads();
    if (threadIdx.x == 0) flag[0] = (nz == 0) ? 1 : 0;   // 1 = int64 layout
}

// ---------------- CSR build ----------------

__global__ void hist_kernel(const int* __restrict__ edges, int* __restrict__ cnt,
                            const int* __restrict__ flag, int E) {
    int i = blockIdx.x * blockDim.x + threadIdx.x;
    if (i >= E) return;
    int is64 = flag[0];
    int r = is64 ? edges[4 * i] : edges[2 * i];
    atomicAdd(&cnt[r], 1);
}

__global__ void scan_kernel(const int* __restrict__ cnt, int* __restrict__ row_start,
                            int* __restrict__ cursor, int N) {
    const int T = 1024;
    int tid = threadIdx.x;
    int C = (N + T - 1) / T;
    int lo = tid * C;
    int hi = lo + C; if (hi > N) hi = N;

    int local = 0;
    for (int i = lo; i < hi; ++i) local += cnt[i];

    int lane = tid & 63, wid = tid >> 6;   // 16 waves
    int v = local;
    #pragma unroll
    for (int off = 1; off < 64; off <<= 1) {
        int y = __shfl_up(v, off, 64);
        if (lane >= off) v += y;
    }
    __shared__ int wsum[16];
    if (lane == 63) wsum[wid] = v;
    __syncthreads();
    if (wid == 0 && lane < 16) {
        int wv = wsum[lane];
        #pragma unroll
        for (int off = 1; off < 16; off <<= 1) {
            int y = __shfl_up(wv, off, 64);
            if (lane >= off) wv += y;
        }
        wsum[lane] = wv;
    }
    __syncthreads();
    int base = (wid > 0 ? wsum[wid - 1] : 0) + (v - local);

    int run = base;
    for (int i = lo; i < hi; ++i) {
        row_start[i] = run;
        cursor[i] = run;
        run += cnt[i];
    }
    if (tid == 0) row_start[N] = wsum[15];
}

__global__ void scatter_kernel(const int* __restrict__ edges, int* __restrict__ cursor,
                               int* __restrict__ edge_send, const int* __restrict__ flag, int E) {
    int i = blockIdx.x * blockDim.x + threadIdx.x;
    if (i >= E) return;
    int is64 = flag[0];
    int r, s;
    if (is64) { r = edges[4 * i]; s = edges[4 * i + 2]; }
    else      { r = edges[2 * i]; s = edges[2 * i + 1]; }
    int pos = atomicAdd(&cursor[r], 1);
    edge_send[pos] = s;
}

// ---------------- Aggregation: one wave per node, lane = feature; writes bf16 hi/lo X ----------------

__global__ void aggregate_kernel(const float* __restrict__ attr, const int* __restrict__ row_start,
                                 const int* __restrict__ edge_send,
                                 unsigned short* __restrict__ Xhi, unsigned short* __restrict__ Xlo,
                                 float* __restrict__ scaleArr, int N) {
    int gwid = (blockIdx.x * blockDim.x + threadIdx.x) >> 6;
    int lane = threadIdx.x & 63;
    if (gwid >= N) return;
    int beg = row_start[gwid], end = row_start[gwid + 1];
    float sum = 0.f, mx = -INFINITY;
    int e = beg;
    for (; e + 4 <= end; e += 4) {
        int s0 = edge_send[e + 0];
        int s1 = edge_send[e + 1];
        int s2 = edge_send[e + 2];
        int s3 = edge_send[e + 3];
        float v0 = attr[(size_t)s0 * F_DIM + lane];
        float v1 = attr[(size_t)s1 * F_DIM + lane];
        float v2 = attr[(size_t)s2 * F_DIM + lane];
        float v3 = attr[(size_t)s3 * F_DIM + lane];
        sum += v0 + v1 + v2 + v3;
        mx = fmaxf(mx, fmaxf(fmaxf(v0, v1), fmaxf(v2, v3)));
    }
    for (; e < end; ++e) {
        int s = edge_send[e];
        float vv = attr[(size_t)s * F_DIM + lane];
        sum += vv;
        mx = fmaxf(mx, vv);
    }
    int c = end - beg;
    float deg = fmaxf((float)c, 1.f);
    float mean = sum / deg;
    if (c == 0) mx = 0.f;
    size_t rb = (size_t)gwid * K_DIM;
    unsigned short h0 = f2bf(mean);
    Xhi[rb + lane] = h0;        Xlo[rb + lane] = f2bf(mean - bf2f(h0));
    unsigned short h1 = f2bf(mx);
    Xhi[rb + 64 + lane] = h1;   Xlo[rb + 64 + lane] = f2bf(mx - bf2f(h1));
    unsigned short h2 = f2bf(sum);
    Xhi[rb + 128 + lane] = h2;  Xlo[rb + 128 + lane] = f2bf(sum - bf2f(h2));
    if (lane == 0) scaleArr[gwid] = logf(deg + 1.f) * 0.43429448190325176f;
}

// ---------------- Weight fold + transpose + bf16 hi/lo split ----------------
// Wt[n][k], n in [0,256): n<128 -> Wa col n ; n>=128 -> Wb col n-128.
// Wa[k] = W[base(k)], Wb[k] = W[base(k)+64] + W[base(k)+128], base(k) = (k/64)*192 + k%64.

__global__ void wprep_kernel(const float* __restrict__ W,
                             unsigned short* __restrict__ WtHi, unsigned short* __restrict__ WtLo) {
    int i = blockIdx.x * blockDim.x + threadIdx.x;
    if (i >= 256 * K_DIM) return;
    int n = i / K_DIM, k = i - n * K_DIM;
    int base = (k >> 6) * 192 + (k & 63);
    float v;
    if (n < 128) v = W[(size_t)base * U_DIM + n];
    else {
        int c = n - 128;
        v = W[(size_t)(base + 64) * U_DIM + c] + W[(size_t)(base + 128) * U_DIM + c];
    }
    unsigned short hi = f2bf(v);
    WtHi[i] = hi;
    WtLo[i] = f2bf(v - bf2f(hi));
}

// ---------------- MFMA GEMM: out = relu(X@Wa + scale*(X@Wb) + b), fused BN stats ----------------
// Block: 128 rows x 256 block-cols (Wa|Wb). 4 waves, wave = 32 rows x 256 cols.
// bf16 split: acc += Ahi*Bhi + Ahi*Blo + Alo*Bhi  (fp32 MFMA accumulate).
// Bhi staged in LDS (XOR-swizzled); Blo read from global (L2-resident, 96 KB).

__launch_bounds__(256)
__global__ void gemm_kernel(const unsigned short* __restrict__ Xhi, const unsigned short* __restrict__ Xlo,
                            const unsigned short* __restrict__ WtHi, const unsigned short* __restrict__ WtLo,
                            const float* __restrict__ scaleArr, const float* __restrict__ bias,
                            float* __restrict__ out, float* __restrict__ stats, int N) {
    __shared__ unsigned short Bh[64 * 256];   // 32 KB, 16B slots, XOR-swizzled (slot ^= n&7)
    __shared__ float sstat[256];

    int tid = threadIdx.x;
    int wave = tid >> 6, lane = tid & 63;
    int q = lane >> 4, c16 = lane & 15;
    int rowBase = blockIdx.x * 128 + wave * 32;

    f32x4 acc[2][16];
    #pragma unroll
    for (int m = 0; m < 2; ++m)
        #pragma unroll
        for (int nt = 0; nt < 16; ++nt)
            acc[m][nt] = (f32x4)(0.f);

    sstat[tid] = 0.f;

    for (int kc = 0; kc < 3; ++kc) {
        // ---- stage W-hi chunk (256 n x 64 k) into LDS, swizzled ----
        #pragma unroll
        for (int i = 0; i < 8; ++i) {
            int s = tid + i * 256;                 // 16B slot id, 0..2047
            int n = s >> 3, ks = s & 7;
            int dslot = (s & ~7) | (ks ^ (n & 7));
            ((us8*)Bh)[dslot] = *(const us8*)&WtHi[(size_t)n * K_DIM + kc * 64 + ks * 8];
        }
        __syncthreads();
        #pragma unroll
        for (int kt = 0; kt < 2; ++kt) {
            // A fragments from global (L2/L3-resident)
            bf16x8 ah[2], al[2];
            #pragma unroll
            for (int m = 0; m < 2; ++m) {
                int r = rowBase + m * 16 + c16;
                if (r > N - 1) r = N - 1;
                size_t aoff = (size_t)r * K_DIM + kc * 64 + kt * 32 + q * 8;
                ah[m] = *(const bf16x8*)&Xhi[aoff];
                al[m] = *(const bf16x8*)&Xlo[aoff];
            }
            #pragma unroll
            for (int nt = 0; nt < 16; ++nt) {
                int n = nt * 16 + c16;
                int ks = kt * 4 + q;
                int slot = (n << 3) | (ks ^ (n & 7));
                bf16x8 bh = ((const bf16x8*)Bh)[slot];
                bf16x8 bl = *(const bf16x8*)&WtLo[(size_t)n * K_DIM + kc * 64 + ks * 8];
                #pragma unroll
                for (int m = 0; m < 2; ++m) {
                    acc[m][nt] = __builtin_amdgcn_mfma_f32_16x16x32_bf16(ah[m], bh, acc[m][nt], 0, 0, 0);
                    acc[m][nt] = __builtin_amdgcn_mfma_f32_16x16x32_bf16(ah[m], bl, acc[m][nt], 0, 0, 0);
                    acc[m][nt] = __builtin_amdgcn_mfma_f32_16x16x32_bf16(al[m], bh, acc[m][nt], 0, 0, 0);
                }
            }
        }
        __syncthreads();
    }

    // ---- epilogue: combine Wa/Wb parts, bias, relu, store + fused BN partial stats ----
    #pragma unroll
    for (int m = 0; m < 2; ++m) {
        int rg = rowBase + m * 16 + q * 4;
        float scv[4]; int vld[4];
        #pragma unroll
        for (int j = 0; j < 4; ++j) {
            int r = rg + j;
            vld[j] = (r < N);
            scv[j] = vld[j] ? scaleArr[r] : 0.f;
        }
        #pragma unroll
        for (int nt = 0; nt < 8; ++nt) {
            int col = nt * 16 + c16;
            float bcol = bias[col];
            f32x4 va = acc[m][nt];
            f32x4 vb = acc[m][nt + 8];
            float s = 0.f, s2 = 0.f;
            #pragma unroll
            for (int j = 0; j < 4; ++j) {
                if (vld[j]) {
                    float h = fmaxf(fmaf(scv[j], vb[j], va[j]) + bcol, 0.f);
                    out[(size_t)(rg + j) * U_DIM + col] = h;
                    s += h;
                    s2 = fmaf(h, h, s2);
                }
            }
            s  += __shfl_xor(s, 16, 64);  s  += __shfl_xor(s, 32, 64);
            s2 += __shfl_xor(s2, 16, 64); s2 += __shfl_xor(s2, 32, 64);
            if (q == 0) {
                atomicAdd(&sstat[col], s);
                atomicAdd(&sstat[128 + col], s2);
            }
        }
    }
    __syncthreads();
    atomicAdd(&stats[tid], sstat[tid]);   // stats[0..127]=sum, [128..255]=sumsq
}

// ---------------- BatchNorm finalize + apply ----------------

__global__ void finalize_kernel(const float* __restrict__ stats, float* __restrict__ ab,
                                const float* __restrict__ gamma, const float* __restrict__ beta, int N) {
    int c = threadIdx.x;   // 128 threads
    float inv = 1.f / (float)N;
    float mean = stats[c] * inv;
    float var = stats[128 + c] * inv - mean * mean;
    float rstd = rsqrtf(var + EPS_LN);
    float sc = gamma[c] * rstd;
    ab[c] = sc;
    ab[128 + c] = fmaf(-mean, sc, beta[c]);
}

__global__ void norm_kernel(float* __restrict__ h, const float* __restrict__ ab, int total4) {
    int i = blockIdx.x * blockDim.x + threadIdx.x;
    if (i >= total4) return;
    int c0 = (i * 4) & 127;
    float4 v = ((const float4*)h)[i];
    float4 o;
    o.x = fmaf(v.x, ab[c0 + 0], ab[128 + c0 + 0]);
    o.y = fmaf(v.y, ab[c0 + 1], ab[128 + c0 + 1]);
    o.z = fmaf(v.z, ab[c0 + 2], ab[128 + c0 + 2]);
    o.w = fmaf(v.w, ab[c0 + 3], ab[128 + c0 + 3]);
    ((float4*)h)[i] = o;
}

// ---------------- launch ----------------

extern "C" void kernel_launch(void* const* d_in, const int* in_sizes, int n_in,
                              void* d_out, int out_size, void* d_ws, size_t ws_size,
                              hipStream_t stream) {
    const float* attr        = (const float*)d_in[0];
    const int*   edges       = (const int*)d_in[1];   // int32 or int64 (probed)
    const float* W           = (const float*)d_in[2];
    const float* bias        = (const float*)d_in[3];
    const float* gamma       = (const float*)d_in[4];
    const float* beta        = (const float*)d_in[5];
    float* out = (float*)d_out;

    const int N = N_NODES, E = E_EDGES;

    char* ws = (char*)d_ws;
    size_t off = 0;
    auto alloc = [&](size_t bytes) -> void* {
        void* p = ws + off;
        off = (off + bytes + 255) & ~(size_t)255;
        return p;
    };
    int*   cnt       = (int*)alloc((size_t)N * 4);
    int*   row_start = (int*)alloc((size_t)(N + 1) * 4);
    int*   cursor    = (int*)alloc((size_t)N * 4);
    int*   edge_send = (int*)alloc((size_t)E * 4);
    float* scaleArr  = (float*)alloc((size_t)N * 4);
    float* stats     = (float*)alloc(512 * 4);
    int*   flag      = (int*)alloc(256);
    unsigned short* WtHi = (unsigned short*)alloc((size_t)256 * K_DIM * 2);
    unsigned short* WtLo = (unsigned short*)alloc((size_t)256 * K_DIM * 2);
    unsigned short* Xhi  = (unsigned short*)alloc((size_t)N * K_DIM * 2);
    unsigned short* Xlo  = (unsigned short*)alloc((size_t)N * K_DIM * 2);
    float* ab = stats + 256;

    hipMemsetAsync(cnt, 0, (size_t)N * 4, stream);
    hipMemsetAsync(stats, 0, 512 * 4, stream);

    probe_kernel<<<1, 256, 0, stream>>>(edges, flag);
    hist_kernel<<<(E + 255) / 256, 256, 0, stream>>>(edges, cnt, flag, E);
    scan_kernel<<<1, 1024, 0, stream>>>(cnt, row_start, cursor, N);
    scatter_kernel<<<(E + 255) / 256, 256, 0, stream>>>(edges, cursor, edge_send, flag, E);
    aggregate_kernel<<<(N + 3) / 4, 256, 0, stream>>>(attr, row_start, edge_send, Xhi, Xlo, scaleArr, N);
    wprep_kernel<<<(256 * K_DIM + 255) / 256, 256, 0, stream>>>(W, WtHi, WtLo);
    gemm_kernel<<<(N + 127) / 128, 256, 0, stream>>>(Xhi, Xlo, WtHi, WtLo, scaleArr, bias, out, stats, N);
    finalize_kernel<<<1, 128, 0, stream>>>(stats, ab, gamma, beta, N);
    norm_kernel<<<(N * U_DIM / 4 + 255) / 256, 256, 0, stream>>>(out, ab, N * U_DIM / 4);
}

// Round 7
// 307.736 us; speedup vs baseline: 1.4093x; 1.2719x over previous
//
#include <hip/hip_runtime.h>
#include <math.h>

#define N_NODES 50000
#define F_DIM 64
#define E_EDGES 800000
#define U_DIM 128
#define K_DIM 192
#define EPS_LN 0.001f
#define CHUNK 1024
#define NCHUNK ((N_NODES + CHUNK - 1) / CHUNK)   // 49 (must be <= 64)

typedef __attribute__((ext_vector_type(8))) short bf16x8;
typedef __attribute__((ext_vector_type(4))) float f32x4;
typedef __attribute__((ext_vector_type(8))) unsigned short us8;

__device__ __forceinline__ unsigned short f2bf(float x) {
    unsigned u = __builtin_bit_cast(unsigned, x);
    unsigned r = (u + 0x7FFFu + ((u >> 16) & 1u)) >> 16;   // RNE
    return (unsigned short)r;
}
__device__ __forceinline__ float bf2f(unsigned short h) {
    unsigned u = ((unsigned)h) << 16;
    return __builtin_bit_cast(float, u);
}

// ---------------- dtype probe ----------------
__global__ void probe_kernel(const int* __restrict__ e, int* __restrict__ flag) {
    __shared__ int nz;
    if (threadIdx.x == 0) nz = 0;
    __syncthreads();
    int i = threadIdx.x;
    if (e[4 * i + 1] != 0 || e[4 * i + 3] != 0) atomicAdd(&nz, 1);
    __syncthreads();
    if (threadIdx.x == 0) flag[0] = (nz == 0) ? 1 : 0;   // 1 = int64 layout
}

// ---------------- CSR build ----------------

__global__ void hist_kernel(const int* __restrict__ edges, int* __restrict__ cnt,
                            const int* __restrict__ flag, int E) {
    int i = blockIdx.x * blockDim.x + threadIdx.x;
    if (i >= E) return;
    int is64 = flag[0];
    int r = is64 ? edges[4 * i] : edges[2 * i];
    atomicAdd(&cnt[r], 1);
}

// ---- 3-phase coalesced scan over cnt[N] -> row_start[N+1] (+cursor copy) ----

__global__ void scan_partial_kernel(const int* __restrict__ cnt, int* __restrict__ partials, int N) {
    __shared__ int ws[4];
    int b = blockIdx.x, tid = threadIdx.x;
    int lane = tid & 63, wid = tid >> 6;
    int idx = b * CHUNK + tid * 4;
    int s = 0;
    if (idx + 4 <= N) {
        int4 v = *(const int4*)&cnt[idx];
        s = v.x + v.y + v.z + v.w;
    } else {
        for (int j = 0; j < 4; ++j) if (idx + j < N) s += cnt[idx + j];
    }
    #pragma unroll
    for (int off = 1; off < 64; off <<= 1) s += __shfl_xor(s, off, 64);
    if (lane == 0) ws[wid] = s;
    __syncthreads();
    if (tid == 0) partials[b] = ws[0] + ws[1] + ws[2] + ws[3];
}

__global__ void scan_partials_kernel(int* __restrict__ partials, int* __restrict__ row_start,
                                     int nchunk, int N) {
    int lane = threadIdx.x;   // 64 threads, nchunk <= 64
    int v = (lane < nchunk) ? partials[lane] : 0;
    int inc = v;
    #pragma unroll
    for (int off = 1; off < 64; off <<= 1) {
        int y = __shfl_up(inc, off, 64);
        if (lane >= off) inc += y;
    }
    if (lane < nchunk) partials[lane] = inc - v;      // exclusive
    if (lane == nchunk - 1) row_start[N] = inc;       // total = E
}

__global__ void scan_final_kernel(const int* __restrict__ cnt, const int* __restrict__ partials,
                                  int* __restrict__ row_start, int* __restrict__ cursor, int N) {
    __shared__ int ws[4];
    int b = blockIdx.x, tid = threadIdx.x;
    int lane = tid & 63, wid = tid >> 6;
    int idx = b * CHUNK + tid * 4;
    int l0 = 0, l1 = 0, l2 = 0, l3 = 0;
    if (idx + 4 <= N) {
        int4 v = *(const int4*)&cnt[idx];
        l0 = v.x; l1 = v.y; l2 = v.z; l3 = v.w;
    } else {
        if (idx + 0 < N) l0 = cnt[idx + 0];
        if (idx + 1 < N) l1 = cnt[idx + 1];
        if (idx + 2 < N) l2 = cnt[idx + 2];
        if (idx + 3 < N) l3 = cnt[idx + 3];
    }
    int t = l0 + l1 + l2 + l3;
    int v = t;
    #pragma unroll
    for (int off = 1; off < 64; off <<= 1) {
        int y = __shfl_up(v, off, 64);
        if (lane >= off) v += y;
    }
    if (lane == 63) ws[wid] = v;
    __syncthreads();
    int wb = 0;
    for (int w = 0; w < 4; ++w) if (w < wid) wb += ws[w];
    int base = partials[b] + wb + (v - t);   // exclusive base for this thread
    int p0 = base, p1 = p0 + l0, p2 = p1 + l1, p3 = p2 + l2;
    if (idx + 4 <= N) {
        int4 pv = make_int4(p0, p1, p2, p3);
        *(int4*)&row_start[idx] = pv;
        *(int4*)&cursor[idx] = pv;
    } else {
        if (idx + 0 < N) { row_start[idx + 0] = p0; cursor[idx + 0] = p0; }
        if (idx + 1 < N) { row_start[idx + 1] = p1; cursor[idx + 1] = p1; }
        if (idx + 2 < N) { row_start[idx + 2] = p2; cursor[idx + 2] = p2; }
        if (idx + 3 < N) { row_start[idx + 3] = p3; cursor[idx + 3] = p3; }
    }
}

__global__ void scatter_kernel(const int* __restrict__ edges, int* __restrict__ cursor,
                               int* __restrict__ edge_send, const int* __restrict__ flag, int E) {
    int i = blockIdx.x * blockDim.x + threadIdx.x;
    if (i >= E) return;
    int is64 = flag[0];
    int r, s;
    if (is64) { r = edges[4 * i]; s = edges[4 * i + 2]; }
    else      { r = edges[2 * i]; s = edges[2 * i + 1]; }
    int pos = atomicAdd(&cursor[r], 1);
    edge_send[pos] = s;
}

// ---------------- Aggregation: one wave per node, lane = feature; writes bf16 hi/lo X ----------------

__global__ void aggregate_kernel(const float* __restrict__ attr, const int* __restrict__ row_start,
                                 const int* __restrict__ edge_send,
                                 unsigned short* __restrict__ Xhi, unsigned short* __restrict__ Xlo,
                                 float* __restrict__ scaleArr, int N) {
    int gwid = (blockIdx.x * blockDim.x + threadIdx.x) >> 6;
    int lane = threadIdx.x & 63;
    if (gwid >= N) return;
    int beg = row_start[gwid], end = row_start[gwid + 1];
    float sum = 0.f, mx = -INFINITY;
    int e = beg;
    for (; e + 4 <= end; e += 4) {
        int s0 = edge_send[e + 0];
        int s1 = edge_send[e + 1];
        int s2 = edge_send[e + 2];
        int s3 = edge_send[e + 3];
        float v0 = attr[(size_t)s0 * F_DIM + lane];
        float v1 = attr[(size_t)s1 * F_DIM + lane];
        float v2 = attr[(size_t)s2 * F_DIM + lane];
        float v3 = attr[(size_t)s3 * F_DIM + lane];
        sum += v0 + v1 + v2 + v3;
        mx = fmaxf(mx, fmaxf(fmaxf(v0, v1), fmaxf(v2, v3)));
    }
    for (; e < end; ++e) {
        int s = edge_send[e];
        float vv = attr[(size_t)s * F_DIM + lane];
        sum += vv;
        mx = fmaxf(mx, vv);
    }
    int c = end - beg;
    float deg = fmaxf((float)c, 1.f);
    float mean = sum / deg;
    if (c == 0) mx = 0.f;
    size_t rb = (size_t)gwid * K_DIM;
    unsigned short h0 = f2bf(mean);
    Xhi[rb + lane] = h0;        Xlo[rb + lane] = f2bf(mean - bf2f(h0));
    unsigned short h1 = f2bf(mx);
    Xhi[rb + 64 + lane] = h1;   Xlo[rb + 64 + lane] = f2bf(mx - bf2f(h1));
    unsigned short h2 = f2bf(sum);
    Xhi[rb + 128 + lane] = h2;  Xlo[rb + 128 + lane] = f2bf(sum - bf2f(h2));
    if (lane == 0) scaleArr[gwid] = logf(deg + 1.f) * 0.43429448190325176f;
}

// ---------------- Weight fold + transpose + bf16 hi/lo split ----------------

__global__ void wprep_kernel(const float* __restrict__ W,
                             unsigned short* __restrict__ WtHi, unsigned short* __restrict__ WtLo) {
    int i = blockIdx.x * blockDim.x + threadIdx.x;
    if (i >= 256 * K_DIM) return;
    int n = i / K_DIM, k = i - n * K_DIM;
    int base = (k >> 6) * 192 + (k & 63);
    float v;
    if (n < 128) v = W[(size_t)base * U_DIM + n];
    else {
        int c = n - 128;
        v = W[(size_t)(base + 64) * U_DIM + c] + W[(size_t)(base + 128) * U_DIM + c];
    }
    unsigned short hi = f2bf(v);
    WtHi[i] = hi;
    WtLo[i] = f2bf(v - bf2f(hi));
}

// ---------------- MFMA GEMM: out = relu(X@Wa + scale*(X@Wb) + b), fused BN stats ----------------

__launch_bounds__(256)
__global__ void gemm_kernel(const unsigned short* __restrict__ Xhi, const unsigned short* __restrict__ Xlo,
                            const unsigned short* __restrict__ WtHi, const unsigned short* __restrict__ WtLo,
                            const float* __restrict__ scaleArr, const float* __restrict__ bias,
                            float* __restrict__ out, float* __restrict__ stats, int N) {
    __shared__ unsigned short Bh[64 * 256];   // 32 KB, 16B slots, XOR-swizzled (slot ^= n&7)
    __shared__ float sstat[256];

    int tid = threadIdx.x;
    int wave = tid >> 6, lane = tid & 63;
    int q = lane >> 4, c16 = lane & 15;
    int rowBase = blockIdx.x * 128 + wave * 32;

    f32x4 acc[2][16];
    #pragma unroll
    for (int m = 0; m < 2; ++m)
        #pragma unroll
        for (int nt = 0; nt < 16; ++nt)
            acc[m][nt] = (f32x4)(0.f);

    sstat[tid] = 0.f;

    for (int kc = 0; kc < 3; ++kc) {
        #pragma unroll
        for (int i = 0; i < 8; ++i) {
            int s = tid + i * 256;                 // 16B slot id, 0..2047
            int n = s >> 3, ks = s & 7;
            int dslot = (s & ~7) | (ks ^ (n & 7));
            ((us8*)Bh)[dslot] = *(const us8*)&WtHi[(size_t)n * K_DIM + kc * 64 + ks * 8];
        }
        __syncthreads();
        #pragma unroll
        for (int kt = 0; kt < 2; ++kt) {
            bf16x8 ah[2], al[2];
            #pragma unroll
            for (int m = 0; m < 2; ++m) {
                int r = rowBase + m * 16 + c16;
                if (r > N - 1) r = N - 1;
                size_t aoff = (size_t)r * K_DIM + kc * 64 + kt * 32 + q * 8;
                ah[m] = *(const bf16x8*)&Xhi[aoff];
                al[m] = *(const bf16x8*)&Xlo[aoff];
            }
            #pragma unroll
            for (int nt = 0; nt < 16; ++nt) {
                int n = nt * 16 + c16;
                int ks = kt * 4 + q;
                int slot = (n << 3) | (ks ^ (n & 7));
                bf16x8 bh = ((const bf16x8*)Bh)[slot];
                bf16x8 bl = *(const bf16x8*)&WtLo[(size_t)n * K_DIM + kc * 64 + ks * 8];
                #pragma unroll
                for (int m = 0; m < 2; ++m) {
                    acc[m][nt] = __builtin_amdgcn_mfma_f32_16x16x32_bf16(ah[m], bh, acc[m][nt], 0, 0, 0);
                    acc[m][nt] = __builtin_amdgcn_mfma_f32_16x16x32_bf16(ah[m], bl, acc[m][nt], 0, 0, 0);
                    acc[m][nt] = __builtin_amdgcn_mfma_f32_16x16x32_bf16(al[m], bh, acc[m][nt], 0, 0, 0);
                }
            }
        }
        __syncthreads();
    }

    #pragma unroll
    for (int m = 0; m < 2; ++m) {
        int rg = rowBase + m * 16 + q * 4;
        float scv[4]; int vld[4];
        #pragma unroll
        for (int j = 0; j < 4; ++j) {
            int r = rg + j;
            vld[j] = (r < N);
            scv[j] = vld[j] ? scaleArr[r] : 0.f;
        }
        #pragma unroll
        for (int nt = 0; nt < 8; ++nt) {
            int col = nt * 16 + c16;
            float bcol = bias[col];
            f32x4 va = acc[m][nt];
            f32x4 vb = acc[m][nt + 8];
            float s = 0.f, s2 = 0.f;
            #pragma unroll
            for (int j = 0; j < 4; ++j) {
                if (vld[j]) {
                    float h = fmaxf(fmaf(scv[j], vb[j], va[j]) + bcol, 0.f);
                    out[(size_t)(rg + j) * U_DIM + col] = h;
                    s += h;
                    s2 = fmaf(h, h, s2);
                }
            }
            s  += __shfl_xor(s, 16, 64);  s  += __shfl_xor(s, 32, 64);
            s2 += __shfl_xor(s2, 16, 64); s2 += __shfl_xor(s2, 32, 64);
            if (q == 0) {
                atomicAdd(&sstat[col], s);
                atomicAdd(&sstat[128 + col], s2);
            }
        }
    }
    __syncthreads();
    atomicAdd(&stats[tid], sstat[tid]);   // stats[0..127]=sum, [128..255]=sumsq
}

// ---------------- BatchNorm finalize + apply ----------------

__global__ void finalize_kernel(const float* __restrict__ stats, float* __restrict__ ab,
                                const float* __restrict__ gamma, const float* __restrict__ beta, int N) {
    int c = threadIdx.x;   // 128 threads
    float inv = 1.f / (float)N;
    float mean = stats[c] * inv;
    float var = stats[128 + c] * inv - mean * mean;
    float rstd = rsqrtf(var + EPS_LN);
    float sc = gamma[c] * rstd;
    ab[c] = sc;
    ab[128 + c] = fmaf(-mean, sc, beta[c]);
}

__global__ void norm_kernel(float* __restrict__ h, const float* __restrict__ ab, int total4) {
    int i = blockIdx.x * blockDim.x + threadIdx.x;
    if (i >= total4) return;
    int c0 = (i * 4) & 127;
    float4 v = ((const float4*)h)[i];
    float4 o;
    o.x = fmaf(v.x, ab[c0 + 0], ab[128 + c0 + 0]);
    o.y = fmaf(v.y, ab[c0 + 1], ab[128 + c0 + 1]);
    o.z = fmaf(v.z, ab[c0 + 2], ab[128 + c0 + 2]);
    o.w = fmaf(v.w, ab[c0 + 3], ab[128 + c0 + 3]);
    ((float4*)h)[i] = o;
}

// ---------------- launch ----------------

extern "C" void kernel_launch(void* const* d_in, const int* in_sizes, int n_in,
                              void* d_out, int out_size, void* d_ws, size_t ws_size,
                              hipStream_t stream) {
    const float* attr        = (const float*)d_in[0];
    const int*   edges       = (const int*)d_in[1];   // int32 or int64 (probed)
    const float* W           = (const float*)d_in[2];
    const float* bias        = (const float*)d_in[3];
    const float* gamma       = (const float*)d_in[4];
    const float* beta        = (const float*)d_in[5];
    float* out = (float*)d_out;

    const int N = N_NODES, E = E_EDGES;

    char* ws = (char*)d_ws;
    size_t off = 0;
    auto alloc = [&](size_t bytes) -> void* {
        void* p = ws + off;
        off = (off + bytes + 255) & ~(size_t)255;
        return p;
    };
    int*   cnt       = (int*)alloc((size_t)N * 4);
    int*   row_start = (int*)alloc((size_t)(N + 1) * 4);
    int*   cursor    = (int*)alloc((size_t)N * 4);
    int*   edge_send = (int*)alloc((size_t)E * 4);
    float* scaleArr  = (float*)alloc((size_t)N * 4);
    float* stats     = (float*)alloc(512 * 4);
    int*   flag      = (int*)alloc(256);
    int*   partials  = (int*)alloc(64 * 4);
    unsigned short* WtHi = (unsigned short*)alloc((size_t)256 * K_DIM * 2);
    unsigned short* WtLo = (unsigned short*)alloc((size_t)256 * K_DIM * 2);
    unsigned short* Xhi  = (unsigned short*)alloc((size_t)N * K_DIM * 2);
    unsigned short* Xlo  = (unsigned short*)alloc((size_t)N * K_DIM * 2);
    float* ab = stats + 256;

    hipMemsetAsync(cnt, 0, (size_t)N * 4, stream);
    hipMemsetAsync(stats, 0, 512 * 4, stream);

    probe_kernel<<<1, 256, 0, stream>>>(edges, flag);
    hist_kernel<<<(E + 255) / 256, 256, 0, stream>>>(edges, cnt, flag, E);
    scan_partial_kernel<<<NCHUNK, 256, 0, stream>>>(cnt, partials, N);
    scan_partials_kernel<<<1, 64, 0, stream>>>(partials, row_start, NCHUNK, N);
    scan_final_kernel<<<NCHUNK, 256, 0, stream>>>(cnt, partials, row_start, cursor, N);
    scatter_kernel<<<(E + 255) / 256, 256, 0, stream>>>(edges, cursor, edge_send, flag, E);
    aggregate_kernel<<<(N + 3) / 4, 256, 0, stream>>>(attr, row_start, edge_send, Xhi, Xlo, scaleArr, N);
    wprep_kernel<<<(256 * K_DIM + 255) / 256, 256, 0, stream>>>(W, WtHi, WtLo);
    gemm_kernel<<<(N + 127) / 128, 256, 0, stream>>>(Xhi, Xlo, WtHi, WtLo, scaleArr, bias, out, stats, N);
    finalize_kernel<<<1, 128, 0, stream>>>(stats, ab, gamma, beta, N);
    norm_kernel<<<(N * U_DIM / 4 + 255) / 256, 256, 0, stream>>>(out, ab, N * U_DIM / 4);
}

// Round 11
// 271.104 us; speedup vs baseline: 1.5997x; 1.1351x over previous
//
#include <hip/hip_runtime.h>
#include <math.h>

#define N_NODES 50000
#define F_DIM 64
#define E_EDGES 800000
#define U_DIM 128
#define K_DIM 192
#define EPS_LN 0.001f
#define CHUNK 1024
#define NCHUNK ((N_NODES + CHUNK - 1) / CHUNK)   // 49 (must be <= 64)

typedef __attribute__((ext_vector_type(8))) short bf16x8;
typedef __attribute__((ext_vector_type(4))) float f32x4;
typedef __attribute__((ext_vector_type(8))) unsigned short us8;

__device__ __forceinline__ unsigned short f2bf(float x) {
    unsigned u = __builtin_bit_cast(unsigned, x);
    unsigned r = (u + 0x7FFFu + ((u >> 16) & 1u)) >> 16;   // RNE
    return (unsigned short)r;
}
__device__ __forceinline__ float bf2f(unsigned short h) {
    unsigned u = ((unsigned)h) << 16;
    return __builtin_bit_cast(float, u);
}

// ---------------- dtype probe ----------------
__global__ void probe_kernel(const int* __restrict__ e, int* __restrict__ flag) {
    __shared__ int nz;
    if (threadIdx.x == 0) nz = 0;
    __syncthreads();
    int i = threadIdx.x;
    if (e[4 * i + 1] != 0 || e[4 * i + 3] != 0) atomicAdd(&nz, 1);
    __syncthreads();
    if (threadIdx.x == 0) flag[0] = (nz == 0) ? 1 : 0;   // 1 = int64 layout
}

// ---------------- CSR build ----------------

__global__ void hist_kernel(const int* __restrict__ edges, int* __restrict__ cnt,
                            const int* __restrict__ flag, int E) {
    int i = blockIdx.x * blockDim.x + threadIdx.x;
    if (i >= E) return;
    int is64 = flag[0];
    int r = is64 ? edges[4 * i] : edges[2 * i];
    atomicAdd(&cnt[r], 1);
}

// ---- 3-phase coalesced scan over cnt[N] -> row_start[N+1] (+cursor copy) ----

__global__ void scan_partial_kernel(const int* __restrict__ cnt, int* __restrict__ partials, int N) {
    __shared__ int ws[4];
    int b = blockIdx.x, tid = threadIdx.x;
    int lane = tid & 63, wid = tid >> 6;
    int idx = b * CHUNK + tid * 4;
    int s = 0;
    if (idx + 4 <= N) {
        int4 v = *(const int4*)&cnt[idx];
        s = v.x + v.y + v.z + v.w;
    } else {
        for (int j = 0; j < 4; ++j) if (idx + j < N) s += cnt[idx + j];
    }
    #pragma unroll
    for (int off = 1; off < 64; off <<= 1) s += __shfl_xor(s, off, 64);
    if (lane == 0) ws[wid] = s;
    __syncthreads();
    if (tid == 0) partials[b] = ws[0] + ws[1] + ws[2] + ws[3];
}

__global__ void scan_partials_kernel(int* __restrict__ partials, int* __restrict__ row_start,
                                     int nchunk, int N) {
    int lane = threadIdx.x;   // 64 threads, nchunk <= 64
    int v = (lane < nchunk) ? partials[lane] : 0;
    int inc = v;
    #pragma unroll
    for (int off = 1; off < 64; off <<= 1) {
        int y = __shfl_up(inc, off, 64);
        if (lane >= off) inc += y;
    }
    if (lane < nchunk) partials[lane] = inc - v;      // exclusive
    if (lane == nchunk - 1) row_start[N] = inc;       // total = E
}

__global__ void scan_final_kernel(const int* __restrict__ cnt, const int* __restrict__ partials,
                                  int* __restrict__ row_start, int* __restrict__ cursor, int N) {
    __shared__ int ws[4];
    int b = blockIdx.x, tid = threadIdx.x;
    int lane = tid & 63, wid = tid >> 6;
    int idx = b * CHUNK + tid * 4;
    int l0 = 0, l1 = 0, l2 = 0, l3 = 0;
    if (idx + 4 <= N) {
        int4 v = *(const int4*)&cnt[idx];
        l0 = v.x; l1 = v.y; l2 = v.z; l3 = v.w;
    } else {
        if (idx + 0 < N) l0 = cnt[idx + 0];
        if (idx + 1 < N) l1 = cnt[idx + 1];
        if (idx + 2 < N) l2 = cnt[idx + 2];
        if (idx + 3 < N) l3 = cnt[idx + 3];
    }
    int t = l0 + l1 + l2 + l3;
    int v = t;
    #pragma unroll
    for (int off = 1; off < 64; off <<= 1) {
        int y = __shfl_up(v, off, 64);
        if (lane >= off) v += y;
    }
    if (lane == 63) ws[wid] = v;
    __syncthreads();
    int wb = 0;
    for (int w = 0; w < 4; ++w) if (w < wid) wb += ws[w];
    int base = partials[b] + wb + (v - t);   // exclusive base for this thread
    int p0 = base, p1 = p0 + l0, p2 = p1 + l1, p3 = p2 + l2;
    if (idx + 4 <= N) {
        int4 pv = make_int4(p0, p1, p2, p3);
        *(int4*)&row_start[idx] = pv;
        *(int4*)&cursor[idx] = pv;
    } else {
        if (idx + 0 < N) { row_start[idx + 0] = p0; cursor[idx + 0] = p0; }
        if (idx + 1 < N) { row_start[idx + 1] = p1; cursor[idx + 1] = p1; }
        if (idx + 2 < N) { row_start[idx + 2] = p2; cursor[idx + 2] = p2; }
        if (idx + 3 < N) { row_start[idx + 3] = p3; cursor[idx + 3] = p3; }
    }
}

__global__ void scatter_kernel(const int* __restrict__ edges, int* __restrict__ cursor,
                               int* __restrict__ edge_send, const int* __restrict__ flag, int E) {
    int i = blockIdx.x * blockDim.x + threadIdx.x;
    if (i >= E) return;
    int is64 = flag[0];
    int r, s;
    if (is64) { r = edges[4 * i]; s = edges[4 * i + 2]; }
    else      { r = edges[2 * i]; s = edges[2 * i + 1]; }
    int pos = atomicAdd(&cursor[r], 1);
    edge_send[pos] = s;
}

// ---------------- Aggregation: one wave per node, lane = feature ----------------
// Indices loaded coalesced (64 per wave) + __shfl broadcast; gathers 4-deep unrolled.

__global__ void aggregate_kernel(const float* __restrict__ attr, const int* __restrict__ row_start,
                                 const int* __restrict__ edge_send,
                                 unsigned short* __restrict__ Xhi, unsigned short* __restrict__ Xlo,
                                 float* __restrict__ scaleArr, int N) {
    int gwid = (blockIdx.x * blockDim.x + threadIdx.x) >> 6;
    int lane = threadIdx.x & 63;
    if (gwid >= N) return;
    int beg = row_start[gwid], end = row_start[gwid + 1];
    float sum = 0.f, mx = -INFINITY;
    for (int base = beg; base < end; base += 64) {
        int cnt = end - base; if (cnt > 64) cnt = 64;
        int ii = base + lane; if (ii >= end) ii = end - 1;
        int il = edge_send[ii];                       // coalesced, one load per wave-chunk
        int j = 0;
        for (; j + 4 <= cnt; j += 4) {
            int s0 = __shfl(il, j + 0, 64);
            int s1 = __shfl(il, j + 1, 64);
            int s2 = __shfl(il, j + 2, 64);
            int s3 = __shfl(il, j + 3, 64);
            float v0 = attr[(size_t)s0 * F_DIM + lane];
            float v1 = attr[(size_t)s1 * F_DIM + lane];
            float v2 = attr[(size_t)s2 * F_DIM + lane];
            float v3 = attr[(size_t)s3 * F_DIM + lane];
            sum += v0 + v1 + v2 + v3;
            mx = fmaxf(mx, fmaxf(fmaxf(v0, v1), fmaxf(v2, v3)));
        }
        for (; j < cnt; ++j) {
            int s = __shfl(il, j, 64);
            float vv = attr[(size_t)s * F_DIM + lane];
            sum += vv;
            mx = fmaxf(mx, vv);
        }
    }
    int c = end - beg;
    float deg = fmaxf((float)c, 1.f);
    float mean = sum / deg;
    if (c == 0) mx = 0.f;
    size_t rb = (size_t)gwid * K_DIM;
    unsigned short h0 = f2bf(mean);
    Xhi[rb + lane] = h0;        Xlo[rb + lane] = f2bf(mean - bf2f(h0));
    unsigned short h1 = f2bf(mx);
    Xhi[rb + 64 + lane] = h1;   Xlo[rb + 64 + lane] = f2bf(mx - bf2f(h1));
    unsigned short h2 = f2bf(sum);
    Xhi[rb + 128 + lane] = h2;  Xlo[rb + 128 + lane] = f2bf(sum - bf2f(h2));
    if (lane == 0) scaleArr[gwid] = logf(deg + 1.f) * 0.43429448190325176f;
}

// ---------------- Weight fold + transpose + bf16 hi/lo split ----------------

__global__ void wprep_kernel(const float* __restrict__ W,
                             unsigned short* __restrict__ WtHi, unsigned short* __restrict__ WtLo) {
    int i = blockIdx.x * blockDim.x + threadIdx.x;
    if (i >= 256 * K_DIM) return;
    int n = i / K_DIM, k = i - n * K_DIM;
    int base = (k >> 6) * 192 + (k & 63);
    float v;
    if (n < 128) v = W[(size_t)base * U_DIM + n];
    else {
        int c = n - 128;
        v = W[(size_t)(base + 64) * U_DIM + c] + W[(size_t)(base + 128) * U_DIM + c];
    }
    unsigned short hi = f2bf(v);
    WtHi[i] = hi;
    WtLo[i] = f2bf(v - bf2f(hi));
}

// ---------------- MFMA GEMM: out = relu(X@Wa + scale*(X@Wb) + b), fused BN stats ----------------
// Block: 64 rows, 4 waves; wave = 16 rows x 256 cols. K-chunk = 32.
// LDS: one 32 KB buffer holds Bhi (slots 0-3 per n) and Blo (slots 4-7 per n),
// XOR-swizzled (slot ^= n&7) -> 2-way max bank aliasing (free).
// bf16 split: acc += Ahi*Bhi + Ahi*Blo + Alo*Bhi (fp32 MFMA accumulate).

__launch_bounds__(256, 3)
__global__ void gemm_kernel(const unsigned short* __restrict__ Xhi, const unsigned short* __restrict__ Xlo,
                            const unsigned short* __restrict__ WtHi, const unsigned short* __restrict__ WtLo,
                            const float* __restrict__ scaleArr, const float* __restrict__ bias,
                            float* __restrict__ out, float* __restrict__ stats, int N) {
    __shared__ unsigned short Bs[2048 * 8];   // 2048 x 16B slots = 32 KB
    __shared__ float sstat[256];

    int tid = threadIdx.x;
    int wave = tid >> 6, lane = tid & 63;
    int q = lane >> 4, c16 = lane & 15;
    int rowBase = blockIdx.x * 64 + wave * 16;

    f32x4 acc[16];
    #pragma unroll
    for (int nt = 0; nt < 16; ++nt) acc[nt] = (f32x4)(0.f);
    sstat[tid] = 0.f;

    int r = rowBase + c16; if (r > N - 1) r = N - 1;
    const size_t rowOff = (size_t)r * K_DIM + q * 8;

    for (int kc = 0; kc < 6; ++kc) {
        // ---- stage hi+lo W chunk (256 n x 32 k) into LDS, swizzled ----
        #pragma unroll
        for (int i = 0; i < 8; ++i) {
            int s = tid + i * 256;                 // 16B slot id, 0..2047
            int n = s >> 3, j = s & 7;
            int dslot = (s & ~7) | (j ^ (n & 7));
            const unsigned short* src = (j < 4)
                ? &WtHi[(size_t)n * K_DIM + kc * 32 + j * 8]
                : &WtLo[(size_t)n * K_DIM + kc * 32 + (j - 4) * 8];
            ((us8*)Bs)[dslot] = *(const us8*)src;
        }
        __syncthreads();
        bf16x8 ah = *(const bf16x8*)&Xhi[rowOff + kc * 32];
        bf16x8 al = *(const bf16x8*)&Xlo[rowOff + kc * 32];
        #pragma unroll
        for (int nt = 0; nt < 16; ++nt) {
            int n = nt * 16 + c16;
            int sh = (n << 3) | (q ^ (n & 7));
            int sl = (n << 3) | ((q + 4) ^ (n & 7));
            bf16x8 bh = ((const bf16x8*)Bs)[sh];
            bf16x8 bl = ((const bf16x8*)Bs)[sl];
            acc[nt] = __builtin_amdgcn_mfma_f32_16x16x32_bf16(ah, bh, acc[nt], 0, 0, 0);
            acc[nt] = __builtin_amdgcn_mfma_f32_16x16x32_bf16(ah, bl, acc[nt], 0, 0, 0);
            acc[nt] = __builtin_amdgcn_mfma_f32_16x16x32_bf16(al, bh, acc[nt], 0, 0, 0);
        }
        __syncthreads();
    }

    // ---- epilogue: combine Wa/Wb, bias, relu, store + fused BN partial stats ----
    int rg = rowBase + q * 4;
    float scv[4]; int vld[4];
    #pragma unroll
    for (int j = 0; j < 4; ++j) {
        int rr = rg + j;
        vld[j] = (rr < N);
        scv[j] = vld[j] ? scaleArr[rr] : 0.f;
    }
    #pragma unroll
    for (int nt = 0; nt < 8; ++nt) {
        int col = nt * 16 + c16;
        float bcol = bias[col];
        f32x4 va = acc[nt];
        f32x4 vb = acc[nt + 8];
        float s = 0.f, s2 = 0.f;
        #pragma unroll
        for (int j = 0; j < 4; ++j) {
            if (vld[j]) {
                float h = fmaxf(fmaf(scv[j], vb[j], va[j]) + bcol, 0.f);
                out[(size_t)(rg + j) * U_DIM + col] = h;
                s += h;
                s2 = fmaf(h, h, s2);
            }
        }
        s  += __shfl_xor(s, 16, 64);  s  += __shfl_xor(s, 32, 64);
        s2 += __shfl_xor(s2, 16, 64); s2 += __shfl_xor(s2, 32, 64);
        if (q == 0) {
            atomicAdd(&sstat[col], s);
            atomicAdd(&sstat[128 + col], s2);
        }
    }
    __syncthreads();
    atomicAdd(&stats[tid], sstat[tid]);   // stats[0..127]=sum, [128..255]=sumsq
}

// ---------------- BatchNorm finalize + apply ----------------

__global__ void finalize_kernel(const float* __restrict__ stats, float* __restrict__ ab,
                                const float* __restrict__ gamma, const float* __restrict__ beta, int N) {
    int c = threadIdx.x;   // 128 threads
    float inv = 1.f / (float)N;
    float mean = stats[c] * inv;
    float var = stats[128 + c] * inv - mean * mean;
    float rstd = rsqrtf(var + EPS_LN);
    float sc = gamma[c] * rstd;
    ab[c] = sc;
    ab[128 + c] = fmaf(-mean, sc, beta[c]);
}

__global__ void norm_kernel(float* __restrict__ h, const float* __restrict__ ab, int total4) {
    int i = blockIdx.x * blockDim.x + threadIdx.x;
    if (i >= total4) return;
    int c0 = (i * 4) & 127;
    float4 v = ((const float4*)h)[i];
    float4 o;
    o.x = fmaf(v.x, ab[c0 + 0], ab[128 + c0 + 0]);
    o.y = fmaf(v.y, ab[c0 + 1], ab[128 + c0 + 1]);
    o.z = fmaf(v.z, ab[c0 + 2], ab[128 + c0 + 2]);
    o.w = fmaf(v.w, ab[c0 + 3], ab[128 + c0 + 3]);
    ((float4*)h)[i] = o;
}

// ---------------- launch ----------------

extern "C" void kernel_launch(void* const* d_in, const int* in_sizes, int n_in,
                              void* d_out, int out_size, void* d_ws, size_t ws_size,
                              hipStream_t stream) {
    const float* attr        = (const float*)d_in[0];
    const int*   edges       = (const int*)d_in[1];   // int32 or int64 (probed)
    const float* W           = (const float*)d_in[2];
    const float* bias        = (const float*)d_in[3];
    const float* gamma       = (const float*)d_in[4];
    const float* beta        = (const float*)d_in[5];
    float* out = (float*)d_out;

    const int N = N_NODES, E = E_EDGES;

    char* ws = (char*)d_ws;
    size_t off = 0;
    auto alloc = [&](size_t bytes) -> void* {
        void* p = ws + off;
        off = (off + bytes + 255) & ~(size_t)255;
        return p;
    };
    int*   cnt       = (int*)alloc((size_t)N * 4);
    int*   row_start = (int*)alloc((size_t)(N + 1) * 4);
    int*   cursor    = (int*)alloc((size_t)N * 4);
    int*   edge_send = (int*)alloc((size_t)E * 4);
    float* scaleArr  = (float*)alloc((size_t)N * 4);
    float* stats     = (float*)alloc(512 * 4);
    int*   flag      = (int*)alloc(256);
    int*   partials  = (int*)alloc(64 * 4);
    unsigned short* WtHi = (unsigned short*)alloc((size_t)256 * K_DIM * 2);
    unsigned short* WtLo = (unsigned short*)alloc((size_t)256 * K_DIM * 2);
    unsigned short* Xhi  = (unsigned short*)alloc((size_t)N * K_DIM * 2);
    unsigned short* Xlo  = (unsigned short*)alloc((size_t)N * K_DIM * 2);
    float* ab = stats + 256;

    hipMemsetAsync(cnt, 0, (size_t)N * 4, stream);
    hipMemsetAsync(stats, 0, 512 * 4, stream);

    probe_kernel<<<1, 256, 0, stream>>>(edges, flag);
    hist_kernel<<<(E + 255) / 256, 256, 0, stream>>>(edges, cnt, flag, E);
    scan_partial_kernel<<<NCHUNK, 256, 0, stream>>>(cnt, partials, N);
    scan_partials_kernel<<<1, 64, 0, stream>>>(partials, row_start, NCHUNK, N);
    scan_final_kernel<<<NCHUNK, 256, 0, stream>>>(cnt, partials, row_start, cursor, N);
    scatter_kernel<<<(E + 255) / 256, 256, 0, stream>>>(edges, cursor, edge_send, flag, E);
    aggregate_kernel<<<(N + 3) / 4, 256, 0, stream>>>(attr, row_start, edge_send, Xhi, Xlo, scaleArr, N);
    wprep_kernel<<<(256 * K_DIM + 255) / 256, 256, 0, stream>>>(W, WtHi, WtLo);
    gemm_kernel<<<(N + 63) / 64, 256, 0, stream>>>(Xhi, Xlo, WtHi, WtLo, scaleArr, bias, out, stats, N);
    finalize_kernel<<<1, 128, 0, stream>>>(stats, ab, gamma, beta, N);
    norm_kernel<<<(N * U_DIM / 4 + 255) / 256, 256, 0, stream>>>(out, ab, N * U_DIM / 4);
}

// Round 13
// 202.128 us; speedup vs baseline: 2.1456x; 1.3412x over previous
//
#include <hip/hip_runtime.h>
#include <math.h>

#define N_NODES 50000
#define F_DIM 64
#define E_EDGES 800000
#define U_DIM 128
#define K_DIM 192
#define EPS_LN 0.001f
#define NB 196           // ceil(N/256) node buckets
#define BN_NODES 256     // nodes per bucket

typedef __attribute__((ext_vector_type(8))) short bf16x8;
typedef __attribute__((ext_vector_type(4))) float f32x4;
typedef __attribute__((ext_vector_type(8))) unsigned short us8;

__device__ __forceinline__ unsigned short f2bf(float x) {
    unsigned u = __builtin_bit_cast(unsigned, x);
    unsigned r = (u + 0x7FFFu + ((u >> 16) & 1u)) >> 16;   // RNE
    return (unsigned short)r;
}
__device__ __forceinline__ float bf2f(unsigned short h) {
    unsigned u = ((unsigned)h) << 16;
    return __builtin_bit_cast(float, u);
}

// ---------------- dtype probe ----------------
__global__ void probe_kernel(const int* __restrict__ e, int* __restrict__ flag) {
    __shared__ int nz;
    if (threadIdx.x == 0) nz = 0;
    __syncthreads();
    int i = threadIdx.x;
    if (e[4 * i + 1] != 0 || e[4 * i + 3] != 0) atomicAdd(&nz, 1);
    __syncthreads();
    if (threadIdx.x == 0) flag[0] = (nz == 0) ? 1 : 0;   // 1 = int64 layout
}

// ---------------- CSR build: 2-level bucket sort, LDS-atomic based ----------------

// Pass A: per-bucket histogram (LDS-staged; 196 device atomics per block).
__global__ void bucket_hist_kernel(const int* __restrict__ edges, const int* __restrict__ flag,
                                   int* __restrict__ bhist, int E) {
    __shared__ int h[NB];
    int tid = threadIdx.x;
    for (int i = tid; i < NB; i += 1024) h[i] = 0;
    __syncthreads();
    int is64 = flag[0];
    int e0 = blockIdx.x * 4096 + tid * 4;
    #pragma unroll
    for (int j = 0; j < 4; ++j) {
        int e = e0 + j;
        if (e < E) {
            int r = is64 ? edges[4 * e] : edges[2 * e];
            atomicAdd(&h[r >> 8], 1);
        }
    }
    __syncthreads();
    for (int i = tid; i < NB; i += 1024) if (h[i]) atomicAdd(&bhist[i], h[i]);
}

// Pass B: exclusive scan of 196 bucket counts -> bucketStart[NB+1], bucketCursor copy.
__global__ void bucket_scan_kernel(const int* __restrict__ bhist, int* __restrict__ bucketStart,
                                   int* __restrict__ bucketCursor, int E) {
    __shared__ int wtot[4];
    int tid = threadIdx.x;             // 256
    int w = tid >> 6, l = tid & 63;
    int v = (tid < NB) ? bhist[tid] : 0;
    int x = v;
    #pragma unroll
    for (int off = 1; off < 64; off <<= 1) {
        int y = __shfl_up(x, off, 64);
        if (l >= off) x += y;
    }
    if (l == 63) wtot[w] = x;
    __syncthreads();
    int add = 0;
    for (int k = 0; k < w; ++k) add += wtot[k];
    int excl = x - v + add;
    if (tid < NB) { bucketStart[tid] = excl; bucketCursor[tid] = excl; }
    if (tid == 0) bucketStart[NB] = E;
}

// Pass C: scatter edges into bucket-contiguous tmp, packed (r<<16)|s (both < 2^16).
// LDS hist gives in-block rank; ONE device atomic per bucket per block.
__global__ void bucket_scatter_kernel(const int* __restrict__ edges, const int* __restrict__ flag,
                                      int* __restrict__ bucketCursor, unsigned int* __restrict__ tmp, int E) {
    __shared__ int h[NB];
    __shared__ int base[NB];
    int tid = threadIdx.x;
    for (int i = tid; i < NB; i += 1024) h[i] = 0;
    __syncthreads();
    int is64 = flag[0];
    int e0 = blockIdx.x * 4096 + tid * 4;
    int rr[4], ss[4], rk[4];
    #pragma unroll
    for (int j = 0; j < 4; ++j) {
        int e = e0 + j;
        rr[j] = -1; ss[j] = 0; rk[j] = 0;
        if (e < E) {
            if (is64) { rr[j] = edges[4 * e]; ss[j] = edges[4 * e + 2]; }
            else      { rr[j] = edges[2 * e]; ss[j] = edges[2 * e + 1]; }
            rk[j] = atomicAdd(&h[rr[j] >> 8], 1);
        }
    }
    __syncthreads();
    for (int i = tid; i < NB; i += 1024) base[i] = h[i] ? atomicAdd(&bucketCursor[i], h[i]) : 0;
    __syncthreads();
    #pragma unroll
    for (int j = 0; j < 4; ++j) {
        if (rr[j] >= 0) {
            int b = rr[j] >> 8;
            tmp[base[b] + rk[j]] = (((unsigned)rr[j]) << 16) | (unsigned)ss[j];
        }
    }
}

// Pass D: per-bucket fine placement. Builds row_start (in-LDS 256-scan) and edge_send.
// All positional atomics are LDS; writes dense within the bucket's region.
__launch_bounds__(1024)
__global__ void fine_scatter_kernel(const unsigned int* __restrict__ tmp, const int* __restrict__ bucketStart,
                                    int* __restrict__ row_start, int* __restrict__ edge_send, int N, int E) {
    __shared__ int cnt[BN_NODES];
    __shared__ int cur[BN_NODES];
    __shared__ int vsave[BN_NODES];
    __shared__ int wtot[4];
    int b = blockIdx.x;
    int nodeBase = b * BN_NODES;
    int tid = threadIdx.x;
    if (tid < BN_NODES) cnt[tid] = 0;
    __syncthreads();
    int start = bucketStart[b], end = bucketStart[b + 1];
    for (int i = start + tid; i < end; i += 1024)
        atomicAdd(&cnt[(tmp[i] >> 16) - nodeBase], 1);
    __syncthreads();
    if (tid < BN_NODES) {
        int w = tid >> 6, l = tid & 63;
        int v = cnt[tid];
        vsave[tid] = v;
        int x = v;
        #pragma unroll
        for (int off = 1; off < 64; off <<= 1) {
            int y = __shfl_up(x, off, 64);
            if (l >= off) x += y;
        }
        cur[tid] = x;                 // inclusive (per 64-wide group)
        if (l == 63) wtot[w] = x;
    }
    __syncthreads();
    if (tid < BN_NODES) {
        int w = tid >> 6;
        int add = 0;
        for (int k = 0; k < w; ++k) add += wtot[k];
        int excl = cur[tid] - vsave[tid] + add;
        int node = nodeBase + tid;
        if (node < N) row_start[node] = start + excl;
        cur[tid] = start + excl;
    }
    if (tid == 0 && b == NB - 1) row_start[N] = E;
    __syncthreads();
    for (int i = start + tid; i < end; i += 1024) {
        unsigned p = tmp[i];
        int rl = (int)(p >> 16) - nodeBase;
        int pos = atomicAdd(&cur[rl], 1);
        edge_send[pos] = (int)(p & 0xFFFFu);
    }
}

// ---------------- Aggregation: one wave per node, lane = feature ----------------
// Indices loaded coalesced (64 per wave) + __shfl broadcast; gathers 4-deep unrolled.

__global__ void aggregate_kernel(const float* __restrict__ attr, const int* __restrict__ row_start,
                                 const int* __restrict__ edge_send,
                                 unsigned short* __restrict__ Xhi, unsigned short* __restrict__ Xlo,
                                 float* __restrict__ scaleArr, int N) {
    int gwid = (blockIdx.x * blockDim.x + threadIdx.x) >> 6;
    int lane = threadIdx.x & 63;
    if (gwid >= N) return;
    int beg = row_start[gwid], end = row_start[gwid + 1];
    float sum = 0.f, mx = -INFINITY;
    for (int base = beg; base < end; base += 64) {
        int cnt = end - base; if (cnt > 64) cnt = 64;
        int ii = base + lane; if (ii >= end) ii = end - 1;
        int il = edge_send[ii];                       // coalesced, one load per wave-chunk
        int j = 0;
        for (; j + 4 <= cnt; j += 4) {
            int s0 = __shfl(il, j + 0, 64);
            int s1 = __shfl(il, j + 1, 64);
            int s2 = __shfl(il, j + 2, 64);
            int s3 = __shfl(il, j + 3, 64);
            float v0 = attr[(size_t)s0 * F_DIM + lane];
            float v1 = attr[(size_t)s1 * F_DIM + lane];
            float v2 = attr[(size_t)s2 * F_DIM + lane];
            float v3 = attr[(size_t)s3 * F_DIM + lane];
            sum += v0 + v1 + v2 + v3;
            mx = fmaxf(mx, fmaxf(fmaxf(v0, v1), fmaxf(v2, v3)));
        }
        for (; j < cnt; ++j) {
            int s = __shfl(il, j, 64);
            float vv = attr[(size_t)s * F_DIM + lane];
            sum += vv;
            mx = fmaxf(mx, vv);
        }
    }
    int c = end - beg;
    float deg = fmaxf((float)c, 1.f);
    float mean = sum / deg;
    if (c == 0) mx = 0.f;
    size_t rb = (size_t)gwid * K_DIM;
    unsigned short h0 = f2bf(mean);
    Xhi[rb + lane] = h0;        Xlo[rb + lane] = f2bf(mean - bf2f(h0));
    unsigned short h1 = f2bf(mx);
    Xhi[rb + 64 + lane] = h1;   Xlo[rb + 64 + lane] = f2bf(mx - bf2f(h1));
    unsigned short h2 = f2bf(sum);
    Xhi[rb + 128 + lane] = h2;  Xlo[rb + 128 + lane] = f2bf(sum - bf2f(h2));
    if (lane == 0) scaleArr[gwid] = logf(deg + 1.f) * 0.43429448190325176f;
}

// ---------------- Weight fold + transpose + bf16 hi/lo split ----------------

__global__ void wprep_kernel(const float* __restrict__ W,
                             unsigned short* __restrict__ WtHi, unsigned short* __restrict__ WtLo) {
    int i = blockIdx.x * blockDim.x + threadIdx.x;
    if (i >= 256 * K_DIM) return;
    int n = i / K_DIM, k = i - n * K_DIM;
    int base = (k >> 6) * 192 + (k & 63);
    float v;
    if (n < 128) v = W[(size_t)base * U_DIM + n];
    else {
        int c = n - 128;
        v = W[(size_t)(base + 64) * U_DIM + c] + W[(size_t)(base + 128) * U_DIM + c];
    }
    unsigned short hi = f2bf(v);
    WtHi[i] = hi;
    WtLo[i] = f2bf(v - bf2f(hi));
}

// ---------------- MFMA GEMM: out = relu(X@Wa + scale*(X@Wb) + b), fused BN stats ----------------
// Block: 64 rows, 4 waves; wave = 16 rows x 256 cols. K-chunk = 32.
// LDS: one 32 KB buffer holds Bhi (slots 0-3 per n) and Blo (slots 4-7 per n),
// XOR-swizzled (slot ^= n&7) -> 2-way max bank aliasing (free).
// bf16 split: acc += Ahi*Bhi + Ahi*Blo + Alo*Bhi (fp32 MFMA accumulate).

__launch_bounds__(256, 3)
__global__ void gemm_kernel(const unsigned short* __restrict__ Xhi, const unsigned short* __restrict__ Xlo,
                            const unsigned short* __restrict__ WtHi, const unsigned short* __restrict__ WtLo,
                            const float* __restrict__ scaleArr, const float* __restrict__ bias,
                            float* __restrict__ out, float* __restrict__ stats, int N) {
    __shared__ unsigned short Bs[2048 * 8];   // 2048 x 16B slots = 32 KB
    __shared__ float sstat[256];

    int tid = threadIdx.x;
    int wave = tid >> 6, lane = tid & 63;
    int q = lane >> 4, c16 = lane & 15;
    int rowBase = blockIdx.x * 64 + wave * 16;

    f32x4 acc[16];
    #pragma unroll
    for (int nt = 0; nt < 16; ++nt) acc[nt] = (f32x4)(0.f);
    sstat[tid] = 0.f;

    int r = rowBase + c16; if (r > N - 1) r = N - 1;
    const size_t rowOff = (size_t)r * K_DIM + q * 8;

    for (int kc = 0; kc < 6; ++kc) {
        // ---- stage hi+lo W chunk (256 n x 32 k) into LDS, swizzled ----
        #pragma unroll
        for (int i = 0; i < 8; ++i) {
            int s = tid + i * 256;                 // 16B slot id, 0..2047
            int n = s >> 3, j = s & 7;
            int dslot = (s & ~7) | (j ^ (n & 7));
            const unsigned short* src = (j < 4)
                ? &WtHi[(size_t)n * K_DIM + kc * 32 + j * 8]
                : &WtLo[(size_t)n * K_DIM + kc * 32 + (j - 4) * 8];
            ((us8*)Bs)[dslot] = *(const us8*)src;
        }
        __syncthreads();
        bf16x8 ah = *(const bf16x8*)&Xhi[rowOff + kc * 32];
        bf16x8 al = *(const bf16x8*)&Xlo[rowOff + kc * 32];
        #pragma unroll
        for (int nt = 0; nt < 16; ++nt) {
            int n = nt * 16 + c16;
            int sh = (n << 3) | (q ^ (n & 7));
            int sl = (n << 3) | ((q + 4) ^ (n & 7));
            bf16x8 bh = ((const bf16x8*)Bs)[sh];
            bf16x8 bl = ((const bf16x8*)Bs)[sl];
            acc[nt] = __builtin_amdgcn_mfma_f32_16x16x32_bf16(ah, bh, acc[nt], 0, 0, 0);
            acc[nt] = __builtin_amdgcn_mfma_f32_16x16x32_bf16(ah, bl, acc[nt], 0, 0, 0);
            acc[nt] = __builtin_amdgcn_mfma_f32_16x16x32_bf16(al, bh, acc[nt], 0, 0, 0);
        }
        __syncthreads();
    }

    // ---- epilogue: combine Wa/Wb, bias, relu, store + fused BN partial stats ----
    int rg = rowBase + q * 4;
    float scv[4]; int vld[4];
    #pragma unroll
    for (int j = 0; j < 4; ++j) {
        int rr = rg + j;
        vld[j] = (rr < N);
        scv[j] = vld[j] ? scaleArr[rr] : 0.f;
    }
    #pragma unroll
    for (int nt = 0; nt < 8; ++nt) {
        int col = nt * 16 + c16;
        float bcol = bias[col];
        f32x4 va = acc[nt];
        f32x4 vb = acc[nt + 8];
        float s = 0.f, s2 = 0.f;
        #pragma unroll
        for (int j = 0; j < 4; ++j) {
            if (vld[j]) {
                float h = fmaxf(fmaf(scv[j], vb[j], va[j]) + bcol, 0.f);
                out[(size_t)(rg + j) * U_DIM + col] = h;
                s += h;
                s2 = fmaf(h, h, s2);
            }
        }
        s  += __shfl_xor(s, 16, 64);  s  += __shfl_xor(s, 32, 64);
        s2 += __shfl_xor(s2, 16, 64); s2 += __shfl_xor(s2, 32, 64);
        if (q == 0) {
            atomicAdd(&sstat[col], s);
            atomicAdd(&sstat[128 + col], s2);
        }
    }
    __syncthreads();
    atomicAdd(&stats[tid], sstat[tid]);   // stats[0..127]=sum, [128..255]=sumsq
}

// ---------------- BatchNorm finalize + apply ----------------

__global__ void finalize_kernel(const float* __restrict__ stats, float* __restrict__ ab,
                                const float* __restrict__ gamma, const float* __restrict__ beta, int N) {
    int c = threadIdx.x;   // 128 threads
    float inv = 1.f / (float)N;
    float mean = stats[c] * inv;
    float var = stats[128 + c] * inv - mean * mean;
    float rstd = rsqrtf(var + EPS_LN);
    float sc = gamma[c] * rstd;
    ab[c] = sc;
    ab[128 + c] = fmaf(-mean, sc, beta[c]);
}

__global__ void norm_kernel(float* __restrict__ h, const float* __restrict__ ab, int total4) {
    int i = blockIdx.x * blockDim.x + threadIdx.x;
    if (i >= total4) return;
    int c0 = (i * 4) & 127;
    float4 v = ((const float4*)h)[i];
    float4 o;
    o.x = fmaf(v.x, ab[c0 + 0], ab[128 + c0 + 0]);
    o.y = fmaf(v.y, ab[c0 + 1], ab[128 + c0 + 1]);
    o.z = fmaf(v.z, ab[c0 + 2], ab[128 + c0 + 2]);
    o.w = fmaf(v.w, ab[c0 + 3], ab[128 + c0 + 3]);
    ((float4*)h)[i] = o;
}

// ---------------- launch ----------------

extern "C" void kernel_launch(void* const* d_in, const int* in_sizes, int n_in,
                              void* d_out, int out_size, void* d_ws, size_t ws_size,
                              hipStream_t stream) {
    const float* attr        = (const float*)d_in[0];
    const int*   edges       = (const int*)d_in[1];   // int32 or int64 (probed)
    const float* W           = (const float*)d_in[2];
    const float* bias        = (const float*)d_in[3];
    const float* gamma       = (const float*)d_in[4];
    const float* beta        = (const float*)d_in[5];
    float* out = (float*)d_out;

    const int N = N_NODES, E = E_EDGES;

    char* ws = (char*)d_ws;
    size_t off = 0;
    auto alloc = [&](size_t bytes) -> void* {
        void* p = ws + off;
        off = (off + bytes + 255) & ~(size_t)255;
        return p;
    };
    int*   row_start    = (int*)alloc((size_t)(N + 1) * 4);
    int*   edge_send    = (int*)alloc((size_t)E * 4);
    unsigned int* tmp   = (unsigned int*)alloc((size_t)E * 4);
    float* scaleArr     = (float*)alloc((size_t)N * 4);
    float* stats        = (float*)alloc(512 * 4);
    int*   flag         = (int*)alloc(256);
    int*   bhist        = (int*)alloc(NB * 4);
    int*   bucketStart  = (int*)alloc((NB + 1) * 4);
    int*   bucketCursor = (int*)alloc(NB * 4);
    unsigned short* WtHi = (unsigned short*)alloc((size_t)256 * K_DIM * 2);
    unsigned short* WtLo = (unsigned short*)alloc((size_t)256 * K_DIM * 2);
    unsigned short* Xhi  = (unsigned short*)alloc((size_t)N * K_DIM * 2);
    unsigned short* Xlo  = (unsigned short*)alloc((size_t)N * K_DIM * 2);
    float* ab = stats + 256;

    hipMemsetAsync(bhist, 0, NB * 4, stream);
    hipMemsetAsync(stats, 0, 512 * 4, stream);

    const int EB = (E + 4095) / 4096;   // 196 edge blocks (1024 thr x 4 edges)

    probe_kernel<<<1, 256, 0, stream>>>(edges, flag);
    bucket_hist_kernel<<<EB, 1024, 0, stream>>>(edges, flag, bhist, E);
    bucket_scan_kernel<<<1, 256, 0, stream>>>(bhist, bucketStart, bucketCursor, E);
    bucket_scatter_kernel<<<EB, 1024, 0, stream>>>(edges, flag, bucketCursor, tmp, E);
    fine_scatter_kernel<<<NB, 1024, 0, stream>>>(tmp, bucketStart, row_start, edge_send, N, E);
    aggregate_kernel<<<(N + 3) / 4, 256, 0, stream>>>(attr, row_start, edge_send, Xhi, Xlo, scaleArr, N);
    wprep_kernel<<<(256 * K_DIM + 255) / 256, 256, 0, stream>>>(W, WtHi, WtLo);
    gemm_kernel<<<(N + 63) / 64, 256, 0, stream>>>(Xhi, Xlo, WtHi, WtLo, scaleArr, bias, out, stats, N);
    finalize_kernel<<<1, 128, 0, stream>>>(stats, ab, gamma, beta, N);
    norm_kernel<<<(N * U_DIM / 4 + 255) / 256, 256, 0, stream>>>(out, ab, N * U_DIM / 4);
}